// Round 7
// baseline (325.501 us; speedup 1.0000x reference)
//
#include <hip/hip_runtime.h>
#include <math.h>

#define N_NODE   100000
#define N_EDGE   500000
#define IN_DIM   128
#define OUT_DIM  128
#define ATTN_DIM 64
#define N_RELTAB 401   // 2*N_REL+1
#define N_QRY    64
#define N_TAU    366

#define SCAN_BLK     256
#define N_SCAN_BLKS  ((N_NODE + SCAN_BLK - 1) / SCAN_BLK)   // 391

#define NB_TABLES    (N_TAU + N_RELTAB + N_QRY + 3)          // 834
#define NB_COUNT     ((N_EDGE + 255) / 256)                  // 1954
#define NB_NODE      ((N_NODE + 63) / 64)                    // 1563

typedef unsigned int  uint;
typedef unsigned short ushort;
typedef __attribute__((ext_vector_type(8))) short bf16x8;
typedef __attribute__((ext_vector_type(4))) float f32x4;

// ---- bf16 helpers (RNE) ----------------------------------------------------
__device__ __forceinline__ float bfl(uint u)  { return __uint_as_float(u << 16); }
__device__ __forceinline__ float bfh(uint u)  { return __uint_as_float(u & 0xFFFF0000u); }
__device__ __forceinline__ uint  f2bfbits(float f) {
    uint u = __float_as_uint(f);
    return (u + 0x7FFFu + ((u >> 16) & 1u)) >> 16;
}
__device__ __forceinline__ uint  pack2(float lo, float hi) {
    return f2bfbits(lo) | (f2bfbits(hi) << 16);
}

// ---------------------------------------------------------------------------
// Kernel 1: build small lookup tables (bf16) + W fragment tables + edge count.
// ---------------------------------------------------------------------------
__global__ __launch_bounds__(256) void build_count(const int* __restrict__ q_rel,
                             const int* __restrict__ q_tau_p,
                             const float* __restrict__ rela_embed,
                             const float* __restrict__ Wr_w,
                             const float* __restrict__ Wqr_w,
                             const float* __restrict__ Wqr_b,
                             const float* __restrict__ Wtau_w,
                             const float* __restrict__ w_t1,
                             const float* __restrict__ b_t1,
                             const float* __restrict__ w_t2,
                             const float* __restrict__ b_t2,
                             const float* __restrict__ W_h_w,
                             const float* __restrict__ W_h_s_w,
                             const float* __restrict__ Ws_w,
                             const int* __restrict__ edges,
                             uint* __restrict__ rel_attn_bf,   // [401][32]
                             uint* __restrict__ qr_attn_bf,    // [64][32]
                             uint* __restrict__ tau_attn_bf,   // [366][32]
                             uint* __restrict__ rel_msg_bf,    // [401][64]
                             uint* __restrict__ tau_msg_bf,    // [366][64]
                             ushort* __restrict__ wfrag_bf,    // [2][2048][8]
                             ushort* __restrict__ wsT_bf,      // [64][128]
                             int* __restrict__ count) {
    __shared__ float srow[IN_DIM];
    __shared__ float sattn[ATTN_DIM];
    const int b = blockIdx.x;
    const int t = threadIdx.x;   // 0..255

    if (b >= NB_TABLES) {
        // ---- edge-count blocks ----
        const int e = (b - NB_TABLES) * 256 + t;
        if (e < N_EDGE) {
            const int obj = edges[(size_t)e * 7 + 6];
            atomicAdd(&count[obj], 1);
        }
        return;
    }

    if (b < N_TAU) {
        if (t < 128) {
            const int q_tau = *q_tau_p;
            const float delta = (float)(b - q_tau);
            srow[t] = w_t1[t] * delta + b_t1[t] + sinf(w_t2[t] * delta + b_t2[t]);
        }
        __syncthreads();
        if (t < 64) tau_msg_bf[b * 64 + t] = pack2(srow[2 * t], srow[2 * t + 1]);
        if (t < ATTN_DIM) {
            float acc = 0.f;
            #pragma unroll 8
            for (int d = 0; d < IN_DIM; ++d)
                acc += srow[d] * Wtau_w[d * ATTN_DIM + t];
            sattn[t] = acc;
        }
        __syncthreads();
        if (t < 32) tau_attn_bf[b * 32 + t] = pack2(sattn[2 * t], sattn[2 * t + 1]);
    } else if (b < N_TAU + N_RELTAB) {
        const int r = b - N_TAU;
        if (t < 128) srow[t] = rela_embed[r * IN_DIM + t];
        __syncthreads();
        if (t < 64) rel_msg_bf[r * 64 + t] = pack2(srow[2 * t], srow[2 * t + 1]);
        if (t < ATTN_DIM) {
            float acc = 0.f;
            #pragma unroll 8
            for (int d = 0; d < IN_DIM; ++d)
                acc += srow[d] * Wr_w[d * ATTN_DIM + t];
            sattn[t] = acc;
        }
        __syncthreads();
        if (t < 32) rel_attn_bf[r * 32 + t] = pack2(sattn[2 * t], sattn[2 * t + 1]);
    } else if (b < N_TAU + N_RELTAB + N_QRY) {
        const int i = b - N_TAU - N_RELTAB;   // 0..63
        const int r = q_rel[i];
        if (t < 128) srow[t] = rela_embed[r * IN_DIM + t];
        __syncthreads();
        if (t < ATTN_DIM) {
            float acc = Wqr_b[t];
            #pragma unroll 8
            for (int d = 0; d < IN_DIM; ++d)
                acc += srow[d] * Wqr_w[d * ATTN_DIM + t];
            sattn[t] = acc;
        }
        __syncthreads();
        if (t < 32) qr_attn_bf[i * 32 + t] = pack2(sattn[2 * t], sattn[2 * t + 1]);
    } else {
        const int w = b - (N_TAU + N_RELTAB + N_QRY);   // 0,1,2
        if (w < 2) {
            // W fragment table for half w: 2048 slots, 8 per thread (128B contig)
            const float* Wsrc = w ? W_h_s_w : W_h_w;
            ushort* dst = wfrag_bf + (size_t)w * 2048 * 8;
            for (int r = 0; r < 8; ++r) {
                const int s  = t * 8 + r;
                const int ct = s >> 8;
                const int ks = (s >> 6) & 3;
                const int l  = s & 63;
                const int lm = l & 15;
                const int lq = l >> 4;
                union { ushort us[8]; uint4 v; } tmp;
                #pragma unroll
                for (int j = 0; j < 8; ++j)
                    tmp.us[j] = (ushort)f2bfbits(Wsrc[(ks * 32 + lq * 8 + j) * 128 + ct * 16 + lm]);
                *(uint4*)(dst + (size_t)s * 8) = tmp.v;
            }
        } else {
            // Ws^T: [n=0..63][k=0..127], thread t = k index
            if (t < 128)
                for (int n = 0; n < 64; ++n)
                    wsT_bf[n * 128 + t] = (ushort)f2bfbits(Ws_w[t * ATTN_DIM + n]);
        }
    }
}

// ---------------------------------------------------------------------------
// Kernel 2: fused cast + MFMA  A_node = bf16(hidden) @ Ws   +  scan_partial
// blocks appended (independent after kernel 1).
// ---------------------------------------------------------------------------
__global__ __launch_bounds__(256) void node_attn_scan(const float* __restrict__ hidden,
                                                      const ushort* __restrict__ wsT_bf,
                                                      uint* __restrict__ hid_bf_u,    // [N][64] uints
                                                      ushort* __restrict__ A_node,    // [N][64] ushorts
                                                      const int* __restrict__ count,
                                                      int* __restrict__ partial) {
    __shared__ int slds[SCAN_BLK];

    if (blockIdx.x >= NB_NODE) {
        // ---- scan_partial block ----
        const int blk = blockIdx.x - NB_NODE;
        const int i = blk * SCAN_BLK + threadIdx.x;
        slds[threadIdx.x] = (i < N_NODE) ? count[i] : 0;
        __syncthreads();
        for (int s = SCAN_BLK / 2; s > 0; s >>= 1) {
            if (threadIdx.x < s) slds[threadIdx.x] += slds[threadIdx.x + s];
            __syncthreads();
        }
        if (threadIdx.x == 0) partial[blk] = slds[0];
        return;
    }

    const int wave = threadIdx.x >> 6;
    const int lane = threadIdx.x & 63;
    const int m    = lane & 15;
    const int quad = lane >> 4;
    const int row0 = blockIdx.x * 64 + wave * 16;
    const int row  = row0 + m;
    const int rowc = min(row, N_NODE - 1);

    const float* hsrc = hidden + (size_t)rowc * IN_DIM;
    ushort* hdst = (ushort*)hid_bf_u + (size_t)rowc * 128;

    bf16x8 afr[4];
    #pragma unroll
    for (int ks = 0; ks < 4; ++ks) {
        const int k0 = ks * 32 + quad * 8;
        const float4 v0 = *(const float4*)(hsrc + k0);
        const float4 v1 = *(const float4*)(hsrc + k0 + 4);
        union { uint u[4]; bf16x8 v; } cvt;
        cvt.u[0] = pack2(v0.x, v0.y);
        cvt.u[1] = pack2(v0.z, v0.w);
        cvt.u[2] = pack2(v1.x, v1.y);
        cvt.u[3] = pack2(v1.z, v1.w);
        afr[ks] = cvt.v;
        if (row < N_NODE) *(bf16x8*)(hdst + k0) = cvt.v;   // 16B store
    }

    f32x4 acc[4] = {};
    #pragma unroll
    for (int ks = 0; ks < 4; ++ks) {
        #pragma unroll
        for (int ct = 0; ct < 4; ++ct) {
            const bf16x8 wfr = *(const bf16x8*)(wsT_bf + (ct * 16 + m) * 128 + ks * 32 + quad * 8);
            // swapped: A = Ws rows (attn dims), B = hidden rows (nodes)
            acc[ct] = __builtin_amdgcn_mfma_f32_16x16x32_bf16(wfr, afr[ks], acc[ct], 0, 0, 0);
        }
    }

    // D: col (lane&15) = node - row0, row (quad*4+r) = attn dim within ct block
    if (row < N_NODE) {
        #pragma unroll
        for (int ct = 0; ct < 4; ++ct) {
            uint2 pk;
            pk.x = pack2(acc[ct][0], acc[ct][1]);
            pk.y = pack2(acc[ct][2], acc[ct][3]);
            *(uint2*)(A_node + (size_t)row * 64 + ct * 16 + quad * 4) = pk;
        }
    }
}

// ---------------------------------------------------------------------------
// Kernel 3: scan_apply v2 — block b sums partial[0..b-1] itself (<=391 ints),
// then does its local scan. Replaces the separate scan_partials launch.
// ---------------------------------------------------------------------------
__global__ __launch_bounds__(SCAN_BLK) void scan_apply(const int* __restrict__ count,
                                                       const int* __restrict__ partial,
                                                       int* __restrict__ off,
                                                       int* __restrict__ cursor) {
    __shared__ int lds[SCAN_BLK];
    __shared__ int base_s;
    const int t = threadIdx.x;
    const int b = blockIdx.x;

    int s = 0;
    if (t < b) s += partial[t];
    if (t + 256 < b) s += partial[t + 256];
    lds[t] = s;
    __syncthreads();
    for (int d = SCAN_BLK / 2; d > 0; d >>= 1) {
        if (t < d) lds[t] += lds[t + d];
        __syncthreads();
    }
    if (t == 0) base_s = lds[0];
    __syncthreads();

    const int i = b * SCAN_BLK + t;
    const int v = (i < N_NODE) ? count[i] : 0;
    lds[t] = v;
    __syncthreads();
    for (int d = 1; d < SCAN_BLK; d <<= 1) {
        int x = (t >= d) ? lds[t - d] : 0;
        __syncthreads();
        lds[t] += x;
        __syncthreads();
    }
    const int excl = base_s + lds[t] - v;
    if (i < N_NODE) { off[i] = excl; cursor[i] = excl; }
    if (i == N_NODE - 1) off[N_NODE] = excl + v;   // = N_EDGE
}

// ---------------------------------------------------------------------------
// Kernel 4: per-edge alpha + CSR fill.  FOUR lanes per edge (16 dims each).
// recs stores PRE-SCALED row offsets (sub*64, rel*64, tidx*64).
// ---------------------------------------------------------------------------
__global__ __launch_bounds__(256) void alpha_fill(const int* __restrict__ edges,
                                                  const int* __restrict__ q_tau_p,
                                                  const uint* __restrict__ A_node_bf,
                                                  const uint* __restrict__ rel_attn_bf,
                                                  const uint* __restrict__ qr_attn_bf,
                                                  const uint* __restrict__ tau_attn_bf,
                                                  const float* __restrict__ w_alpha_w,
                                                  const float* __restrict__ w_alpha_b,
                                                  int* __restrict__ cursor,
                                                  int4* __restrict__ recs) {
    const int t = threadIdx.x;
    const int q = t & 3;                        // lane-in-edge: dims [q*16, q*16+16)
    const int e = blockIdx.x * 64 + (t >> 2);   // 64 edges per 256-thread block
    if (e >= N_EDGE) return;

    const int* ed = edges + (size_t)e * 7;
    const int r_idx = ed[0];
    const int rel   = ed[2];
    const int tau   = ed[4];
    const int sub   = ed[5];
    const int obj   = ed[6];
    const int q_tau = *q_tau_p;
    const int tidx  = (tau >= 0) ? tau : q_tau;

    const uint4*  pa = (const uint4*)(A_node_bf  + (size_t)sub * 32) + q * 2;
    const uint4*  pr = (const uint4*)(rel_attn_bf + rel   * 32) + q * 2;
    const uint4*  pq = (const uint4*)(qr_attn_bf  + r_idx * 32) + q * 2;
    const uint4*  pt = (const uint4*)(tau_attn_bf + tidx  * 32) + q * 2;
    const float4* wv = (const float4*)w_alpha_w + q * 4;

    float acc = 0.f;

#define DOT_UINT(va, vr, vq, vt, wlo, whi) do {                                  \
        const float x0 = bfl(va) + bfl(vr) + bfl(vq) + bfl(vt);                  \
        const float x1 = bfh(va) + bfh(vr) + bfh(vq) + bfh(vt);                  \
        acc = fmaf(fmaxf(x0, 0.f), (wlo), fmaf(fmaxf(x1, 0.f), (whi), acc));     \
    } while (0)

    #pragma unroll
    for (int c = 0; c < 2; ++c) {
        const uint4  ua = pa[c];
        const uint4  ur = pr[c];
        const uint4  uq = pq[c];
        const uint4  ut = pt[c];
        const float4 w0 = wv[c * 2];
        const float4 w1 = wv[c * 2 + 1];
        DOT_UINT(ua.x, ur.x, uq.x, ut.x, w0.x, w0.y);
        DOT_UINT(ua.y, ur.y, uq.y, ut.y, w0.z, w0.w);
        DOT_UINT(ua.z, ur.z, uq.z, ut.z, w1.x, w1.y);
        DOT_UINT(ua.w, ur.w, uq.w, ut.w, w1.z, w1.w);
    }
#undef DOT_UINT

    // reduce across the quad (lanes q=0..3 of this edge)
    acc += __shfl_xor(acc, 1, 64);
    acc += __shfl_xor(acc, 2, 64);

    if (q == 0) {
        const float alpha = 1.f / (1.f + __expf(-(acc + w_alpha_b[0])));
        const int pos = atomicAdd(&cursor[obj], 1);
        recs[pos] = make_int4(sub * 64, rel * 64, tidx * 64, __float_as_int(alpha));
    }
}

// ---------------------------------------------------------------------------
// Kernel 5: FUSED aggregate + final GEMM.  (256 thr, 4 waves, 16 nodes/block.)
// v4 phase 1: TWO edges per wave via half-waves. lane = (h = edge-of-pair,
// c = uint2 column -> dims 4c..4c+3). Each gather instr reads 8B/lane and
// covers two edges' full 256B rows -> gather instrs & per-edge latency chain
// HALVED (6 gathers / 4 edges). Cross-half combine = 8 shfl_xor(32) per node.
// LDS swizzle layout identical to v3 (uint w holds dims 2w,2w+1).
// ---------------------------------------------------------------------------
__global__ __launch_bounds__(256) void agg_gemm(const int* __restrict__ off,
                                                const int4* __restrict__ recs,
                                                const uint* __restrict__ hid_bf,
                                                const uint* __restrict__ rel_msg_bf,
                                                const uint* __restrict__ tau_msg_bf,
                                                const ushort* __restrict__ wfrag,
                                                float* __restrict__ out) {
    __shared__ uint lagg[2 * 16 * 64];   // 8 KB: [half][node16][64 uints], swizzled

    const int wave = threadIdx.x >> 6;
    const int lane = threadIdx.x & 63;
    const int h    = lane >> 5;          // which edge of the pair
    const int c    = lane & 31;          // uint2 column: uints 2c,2c+1 = dims 4c..4c+3
    const int tile = blockIdx.x * 16;

    // ---- phase 1: aggregate (4 nodes per wave, 2 pairs = 4 edges per iter) ----
    #pragma unroll
    for (int k = 0; k < 4; ++k) {
        const int n16 = wave * 4 + k;
        const int n = tile + n16;
        const int j0 = off[n];
        const int j1 = off[n + 1];

        float t0 = 0.f, t1 = 0.f, t2 = 0.f, t3 = 0.f;
        float a0 = 0.f, a1 = 0.f, a2 = 0.f, a3 = 0.f;

        for (int j = j0; j < j1; j += 4) {
            const int eA = j + h;
            const int eB = j + 2 + h;
            const int4 rA = recs[min(eA, j1 - 1)];
            const int4 rB = recs[min(eB, j1 - 1)];

            const uint2 hA = *(const uint2*)(hid_bf     + (uint)rA.x + 2 * c);
            const uint2 gA = *(const uint2*)(rel_msg_bf + rA.y       + 2 * c);
            const uint2 uA = *(const uint2*)(tau_msg_bf + rA.z       + 2 * c);
            const uint2 hB = *(const uint2*)(hid_bf     + (uint)rB.x + 2 * c);
            const uint2 gB = *(const uint2*)(rel_msg_bf + rB.y       + 2 * c);
            const uint2 uB = *(const uint2*)(tau_msg_bf + rB.z       + 2 * c);

#define ACC_PAIR(hh, gg, uu, rr, ee) do {                                        \
            const bool vld = (ee) < j1;                                          \
            const float al = __int_as_float((rr).w);                             \
            float m0 = bfl((hh).x) + bfl((gg).x) + bfl((uu).x);                  \
            float m1 = bfh((hh).x) + bfh((gg).x) + bfh((uu).x);                  \
            float m2 = bfl((hh).y) + bfl((gg).y) + bfl((uu).y);                  \
            float m3 = bfh((hh).y) + bfh((gg).y) + bfh((uu).y);                  \
            m0 = vld ? m0 : 0.f;  m1 = vld ? m1 : 0.f;                           \
            m2 = vld ? m2 : 0.f;  m3 = vld ? m3 : 0.f;                           \
            t0 += m0;  t1 += m1;  t2 += m2;  t3 += m3;                           \
            a0 = fmaf(al, m0, a0);  a1 = fmaf(al, m1, a1);                       \
            a2 = fmaf(al, m2, a2);  a3 = fmaf(al, m3, a3);                       \
        } while (0)

            ACC_PAIR(hA, gA, uA, rA, eA);
            ACC_PAIR(hB, gB, uB, rB, eB);
#undef ACC_PAIR
        }

        // combine the two half-wave partial sums (all 64 lanes participate)
        t0 += __shfl_xor(t0, 32, 64);  t1 += __shfl_xor(t1, 32, 64);
        t2 += __shfl_xor(t2, 32, 64);  t3 += __shfl_xor(t3, 32, 64);
        a0 += __shfl_xor(a0, 32, 64);  a1 += __shfl_xor(a1, 32, 64);
        a2 += __shfl_xor(a2, 32, 64);  a3 += __shfl_xor(a3, 32, 64);

        if (h == 0) {
            const int kx  = n16 & 7;
            const int idx = (((c >> 1) ^ kx) << 2) | ((2 * c) & 3);   // swizzled uint index
            uint2 pa, pt;
            pa.x = pack2(a0, a1);            pa.y = pack2(a2, a3);
            pt.x = pack2(t0 - a0, t1 - a1);  pt.y = pack2(t2 - a2, t3 - a3);
            *(uint2*)&lagg[n16 * 64 + idx]        = pa;
            *(uint2*)&lagg[1024 + n16 * 64 + idx] = pt;
        }
    }
    __syncthreads();

    // ---- phase 2: GEMM (wave w: half = w&1, ct in [(w>>1)*4, +4)) ----
    const int half = wave & 1;
    const int ctg  = (wave >> 1) * 4;
    const int m    = lane & 15;
    const int quad = lane >> 4;

    bf16x8 bfrag[4];
    #pragma unroll
    for (int ks = 0; ks < 4; ++ks) {
        const int g = (ks * 4 + quad) ^ (m & 7);
        bfrag[ks] = *(const bf16x8*)&lagg[half * 1024 + m * 64 + g * 4];
    }

    f32x4 acc[4] = {};
    #pragma unroll
    for (int ks = 0; ks < 4; ++ks) {
        #pragma unroll
        for (int cc = 0; cc < 4; ++cc) {
            const bf16x8 wfr = *(const bf16x8*)(wfrag +
                ((size_t)(((half * 8 + ctg + cc) * 4 + ks) * 64 + lane)) * 8);
            acc[cc] = __builtin_amdgcn_mfma_f32_16x16x32_bf16(wfr, bfrag[ks], acc[cc], 0, 0, 0);
        }
    }

    // D: col (lane&15) = node, row (quad*4+r) = out dim within (ctg+cc)*16 block
    float* O = out + (size_t)half * N_NODE * 128 + (size_t)(tile + m) * 128;
    #pragma unroll
    for (int cc = 0; cc < 4; ++cc)
        *(f32x4*)(O + (ctg + cc) * 16 + quad * 4) = acc[cc];
}

// ---------------------------------------------------------------------------
extern "C" void kernel_launch(void* const* d_in, const int* in_sizes, int n_in,
                              void* d_out, int out_size, void* d_ws, size_t ws_size,
                              hipStream_t stream) {
    const int*   q_rel      = (const int*)d_in[1];
    const int*   q_tau_p    = (const int*)d_in[2];
    const float* hidden     = (const float*)d_in[3];
    const int*   edges      = (const int*)d_in[4];
    const float* rela_embed = (const float*)d_in[7];
    const float* Ws_w       = (const float*)d_in[8];
    const float* Wr_w       = (const float*)d_in[9];
    const float* Wqr_w      = (const float*)d_in[10];
    const float* Wqr_b      = (const float*)d_in[11];
    const float* Wtau_w     = (const float*)d_in[12];
    const float* w_alpha_w  = (const float*)d_in[13];
    const float* w_alpha_b  = (const float*)d_in[14];
    const float* W_h_w      = (const float*)d_in[15];
    const float* W_h_s_w    = (const float*)d_in[16];
    const float* w_t1       = (const float*)d_in[17];
    const float* b_t1       = (const float*)d_in[18];
    const float* w_t2       = (const float*)d_in[19];
    const float* b_t2       = (const float*)d_in[20];

    // ---- workspace layout (16B-aligned chunks) ----
    char* p = (char*)d_ws;
    uint* hid_bf      = (uint*)p;                 p += (size_t)N_NODE * 64 * 4;        // 25.6 MB
    uint* A_node_bf   = (uint*)p;                 p += (size_t)N_NODE * 32 * 4;        // 12.8 MB
    int4* recs        = (int4*)p;                 p += (size_t)N_EDGE * 16;            // 8 MB
    uint* rel_attn_bf = (uint*)p;                 p += N_RELTAB * 32 * 4;
    uint* qr_attn_bf  = (uint*)p;                 p += N_QRY * 32 * 4;
    uint* tau_attn_bf = (uint*)p;                 p += N_TAU * 32 * 4;
    uint* rel_msg_bf  = (uint*)p;                 p += N_RELTAB * 64 * 4;
    uint* tau_msg_bf  = (uint*)p;                 p += N_TAU * 64 * 4;
    ushort* wfrag_bf  = (ushort*)p;               p += (size_t)2 * 2048 * 8 * 2;       // 64 KB
    ushort* wsT_bf    = (ushort*)p;               p += (size_t)64 * 128 * 2;           // 16 KB
    int*  count       = (int*)p;                  p += N_NODE * 4;
    int*  off         = (int*)p;                  p += (N_NODE + 1) * 4;
    int*  cursor      = (int*)p;                  p += N_NODE * 4;
    int*  partial     = (int*)p;                  p += N_SCAN_BLKS * 4;
    int*  blk_off     = (int*)p;                  p += N_SCAN_BLKS * 4;

    hipMemsetAsync(count, 0, (size_t)N_NODE * sizeof(int), stream);

    build_count<<<dim3(NB_TABLES + NB_COUNT), dim3(256), 0, stream>>>(
        q_rel, q_tau_p, rela_embed, Wr_w, Wqr_w, Wqr_b, Wtau_w,
        w_t1, b_t1, w_t2, b_t2, W_h_w, W_h_s_w, Ws_w, edges,
        rel_attn_bf, qr_attn_bf, tau_attn_bf, rel_msg_bf, tau_msg_bf,
        wfrag_bf, wsT_bf, count);

    node_attn_scan<<<dim3(NB_NODE + N_SCAN_BLKS), dim3(256), 0, stream>>>(
        hidden, wsT_bf, hid_bf, (ushort*)A_node_bf, count, partial);

    scan_apply<<<dim3(N_SCAN_BLKS), dim3(SCAN_BLK), 0, stream>>>(count, partial, off, cursor);

    alpha_fill<<<dim3((N_EDGE + 63) / 64), dim3(256), 0, stream>>>(
        edges, q_tau_p, A_node_bf, rel_attn_bf, qr_attn_bf, tau_attn_bf,
        w_alpha_w, w_alpha_b, cursor, recs);

    agg_gemm<<<dim3(N_NODE / 16), dim3(256), 0, stream>>>(
        off, recs, hid_bf, rel_msg_bf, tau_msg_bf, wfrag_bf, (float*)d_out);
}

// Round 8
// 310.716 us; speedup vs baseline: 1.0476x; 1.0476x over previous
//
#include <hip/hip_runtime.h>
#include <math.h>

#define N_NODE   100000
#define N_EDGE   500000
#define IN_DIM   128
#define OUT_DIM  128
#define ATTN_DIM 64
#define N_RELTAB 401   // 2*N_REL+1
#define N_QRY    64
#define N_TAU    366

#define SCAN_BLK     256
#define N_SCAN_BLKS  ((N_NODE + SCAN_BLK - 1) / SCAN_BLK)   // 391

#define NB_TABLES    (N_TAU + N_RELTAB + N_QRY + 3)          // 834
#define NB_COUNT     ((N_EDGE + 255) / 256)                  // 1954
#define NB_NODE      ((N_NODE + 63) / 64)                    // 1563

#define REC_CAP      768    // LDS rec buffer (12 KB); avg block needs ~80

typedef unsigned int  uint;
typedef unsigned short ushort;
typedef __attribute__((ext_vector_type(8))) short bf16x8;
typedef __attribute__((ext_vector_type(4))) float f32x4;

// ---- bf16 helpers (RNE) ----------------------------------------------------
__device__ __forceinline__ float bfl(uint u)  { return __uint_as_float(u << 16); }
__device__ __forceinline__ float bfh(uint u)  { return __uint_as_float(u & 0xFFFF0000u); }
__device__ __forceinline__ uint  f2bfbits(float f) {
    uint u = __float_as_uint(f);
    return (u + 0x7FFFu + ((u >> 16) & 1u)) >> 16;
}
__device__ __forceinline__ uint  pack2(float lo, float hi) {
    return f2bfbits(lo) | (f2bfbits(hi) << 16);
}

// ---------------------------------------------------------------------------
// Kernel 1: build small lookup tables (bf16) + W fragment tables + edge count.
// ---------------------------------------------------------------------------
__global__ __launch_bounds__(256) void build_count(const int* __restrict__ q_rel,
                             const int* __restrict__ q_tau_p,
                             const float* __restrict__ rela_embed,
                             const float* __restrict__ Wr_w,
                             const float* __restrict__ Wqr_w,
                             const float* __restrict__ Wqr_b,
                             const float* __restrict__ Wtau_w,
                             const float* __restrict__ w_t1,
                             const float* __restrict__ b_t1,
                             const float* __restrict__ w_t2,
                             const float* __restrict__ b_t2,
                             const float* __restrict__ W_h_w,
                             const float* __restrict__ W_h_s_w,
                             const float* __restrict__ Ws_w,
                             const int* __restrict__ edges,
                             uint* __restrict__ rel_attn_bf,   // [401][32]
                             uint* __restrict__ qr_attn_bf,    // [64][32]
                             uint* __restrict__ tau_attn_bf,   // [366][32]
                             uint* __restrict__ rel_msg_bf,    // [401][64]
                             uint* __restrict__ tau_msg_bf,    // [366][64]
                             ushort* __restrict__ wfrag_bf,    // [2][2048][8]
                             ushort* __restrict__ wsT_bf,      // [64][128]
                             int* __restrict__ count) {
    __shared__ float srow[IN_DIM];
    __shared__ float sattn[ATTN_DIM];
    const int b = blockIdx.x;
    const int t = threadIdx.x;   // 0..255

    if (b >= NB_TABLES) {
        // ---- edge-count blocks ----
        const int e = (b - NB_TABLES) * 256 + t;
        if (e < N_EDGE) {
            const int obj = edges[(size_t)e * 7 + 6];
            atomicAdd(&count[obj], 1);
        }
        return;
    }

    if (b < N_TAU) {
        if (t < 128) {
            const int q_tau = *q_tau_p;
            const float delta = (float)(b - q_tau);
            srow[t] = w_t1[t] * delta + b_t1[t] + sinf(w_t2[t] * delta + b_t2[t]);
        }
        __syncthreads();
        if (t < 64) tau_msg_bf[b * 64 + t] = pack2(srow[2 * t], srow[2 * t + 1]);
        if (t < ATTN_DIM) {
            float acc = 0.f;
            #pragma unroll 8
            for (int d = 0; d < IN_DIM; ++d)
                acc += srow[d] * Wtau_w[d * ATTN_DIM + t];
            sattn[t] = acc;
        }
        __syncthreads();
        if (t < 32) tau_attn_bf[b * 32 + t] = pack2(sattn[2 * t], sattn[2 * t + 1]);
    } else if (b < N_TAU + N_RELTAB) {
        const int r = b - N_TAU;
        if (t < 128) srow[t] = rela_embed[r * IN_DIM + t];
        __syncthreads();
        if (t < 64) rel_msg_bf[r * 64 + t] = pack2(srow[2 * t], srow[2 * t + 1]);
        if (t < ATTN_DIM) {
            float acc = 0.f;
            #pragma unroll 8
            for (int d = 0; d < IN_DIM; ++d)
                acc += srow[d] * Wr_w[d * ATTN_DIM + t];
            sattn[t] = acc;
        }
        __syncthreads();
        if (t < 32) rel_attn_bf[r * 32 + t] = pack2(sattn[2 * t], sattn[2 * t + 1]);
    } else if (b < N_TAU + N_RELTAB + N_QRY) {
        const int i = b - N_TAU - N_RELTAB;   // 0..63
        const int r = q_rel[i];
        if (t < 128) srow[t] = rela_embed[r * IN_DIM + t];
        __syncthreads();
        if (t < ATTN_DIM) {
            float acc = Wqr_b[t];
            #pragma unroll 8
            for (int d = 0; d < IN_DIM; ++d)
                acc += srow[d] * Wqr_w[d * ATTN_DIM + t];
            sattn[t] = acc;
        }
        __syncthreads();
        if (t < 32) qr_attn_bf[i * 32 + t] = pack2(sattn[2 * t], sattn[2 * t + 1]);
    } else {
        const int w = b - (N_TAU + N_RELTAB + N_QRY);   // 0,1,2
        if (w < 2) {
            // W fragment table for half w: 2048 slots, 8 per thread (128B contig)
            const float* Wsrc = w ? W_h_s_w : W_h_w;
            ushort* dst = wfrag_bf + (size_t)w * 2048 * 8;
            for (int r = 0; r < 8; ++r) {
                const int s  = t * 8 + r;
                const int ct = s >> 8;
                const int ks = (s >> 6) & 3;
                const int l  = s & 63;
                const int lm = l & 15;
                const int lq = l >> 4;
                union { ushort us[8]; uint4 v; } tmp;
                #pragma unroll
                for (int j = 0; j < 8; ++j)
                    tmp.us[j] = (ushort)f2bfbits(Wsrc[(ks * 32 + lq * 8 + j) * 128 + ct * 16 + lm]);
                *(uint4*)(dst + (size_t)s * 8) = tmp.v;
            }
        } else {
            // Ws^T: [n=0..63][k=0..127], thread t = k index
            if (t < 128)
                for (int n = 0; n < 64; ++n)
                    wsT_bf[n * 128 + t] = (ushort)f2bfbits(Ws_w[t * ATTN_DIM + n]);
        }
    }
}

// ---------------------------------------------------------------------------
// Kernel 2: fused cast + MFMA  A_node = bf16(hidden) @ Ws   +  scan_partial
// blocks appended (independent after kernel 1).
// ---------------------------------------------------------------------------
__global__ __launch_bounds__(256) void node_attn_scan(const float* __restrict__ hidden,
                                                      const ushort* __restrict__ wsT_bf,
                                                      uint* __restrict__ hid_bf_u,    // [N][64] uints
                                                      ushort* __restrict__ A_node,    // [N][64] ushorts
                                                      const int* __restrict__ count,
                                                      int* __restrict__ partial) {
    __shared__ int slds[SCAN_BLK];

    if (blockIdx.x >= NB_NODE) {
        // ---- scan_partial block ----
        const int blk = blockIdx.x - NB_NODE;
        const int i = blk * SCAN_BLK + threadIdx.x;
        slds[threadIdx.x] = (i < N_NODE) ? count[i] : 0;
        __syncthreads();
        for (int s = SCAN_BLK / 2; s > 0; s >>= 1) {
            if (threadIdx.x < s) slds[threadIdx.x] += slds[threadIdx.x + s];
            __syncthreads();
        }
        if (threadIdx.x == 0) partial[blk] = slds[0];
        return;
    }

    const int wave = threadIdx.x >> 6;
    const int lane = threadIdx.x & 63;
    const int m    = lane & 15;
    const int quad = lane >> 4;
    const int row0 = blockIdx.x * 64 + wave * 16;
    const int row  = row0 + m;
    const int rowc = min(row, N_NODE - 1);

    const float* hsrc = hidden + (size_t)rowc * IN_DIM;
    ushort* hdst = (ushort*)hid_bf_u + (size_t)rowc * 128;

    bf16x8 afr[4];
    #pragma unroll
    for (int ks = 0; ks < 4; ++ks) {
        const int k0 = ks * 32 + quad * 8;
        const float4 v0 = *(const float4*)(hsrc + k0);
        const float4 v1 = *(const float4*)(hsrc + k0 + 4);
        union { uint u[4]; bf16x8 v; } cvt;
        cvt.u[0] = pack2(v0.x, v0.y);
        cvt.u[1] = pack2(v0.z, v0.w);
        cvt.u[2] = pack2(v1.x, v1.y);
        cvt.u[3] = pack2(v1.z, v1.w);
        afr[ks] = cvt.v;
        if (row < N_NODE) *(bf16x8*)(hdst + k0) = cvt.v;   // 16B store
    }

    f32x4 acc[4] = {};
    #pragma unroll
    for (int ks = 0; ks < 4; ++ks) {
        #pragma unroll
        for (int ct = 0; ct < 4; ++ct) {
            const bf16x8 wfr = *(const bf16x8*)(wsT_bf + (ct * 16 + m) * 128 + ks * 32 + quad * 8);
            // swapped: A = Ws rows (attn dims), B = hidden rows (nodes)
            acc[ct] = __builtin_amdgcn_mfma_f32_16x16x32_bf16(wfr, afr[ks], acc[ct], 0, 0, 0);
        }
    }

    // D: col (lane&15) = node - row0, row (quad*4+r) = attn dim within ct block
    if (row < N_NODE) {
        #pragma unroll
        for (int ct = 0; ct < 4; ++ct) {
            uint2 pk;
            pk.x = pack2(acc[ct][0], acc[ct][1]);
            pk.y = pack2(acc[ct][2], acc[ct][3]);
            *(uint2*)(A_node + (size_t)row * 64 + ct * 16 + quad * 4) = pk;
        }
    }
}

// ---------------------------------------------------------------------------
// Kernel 3: scan_apply — block b sums partial[0..b-1] itself (<=391 ints),
// then does its local scan. (No separate scan_partials launch.)
// ---------------------------------------------------------------------------
__global__ __launch_bounds__(SCAN_BLK) void scan_apply(const int* __restrict__ count,
                                                       const int* __restrict__ partial,
                                                       int* __restrict__ off,
                                                       int* __restrict__ cursor) {
    __shared__ int lds[SCAN_BLK];
    __shared__ int base_s;
    const int t = threadIdx.x;
    const int b = blockIdx.x;

    int s = 0;
    if (t < b) s += partial[t];
    if (t + 256 < b) s += partial[t + 256];
    lds[t] = s;
    __syncthreads();
    for (int d = SCAN_BLK / 2; d > 0; d >>= 1) {
        if (t < d) lds[t] += lds[t + d];
        __syncthreads();
    }
    if (t == 0) base_s = lds[0];
    __syncthreads();

    const int i = b * SCAN_BLK + t;
    const int v = (i < N_NODE) ? count[i] : 0;
    lds[t] = v;
    __syncthreads();
    for (int d = 1; d < SCAN_BLK; d <<= 1) {
        int x = (t >= d) ? lds[t - d] : 0;
        __syncthreads();
        lds[t] += x;
        __syncthreads();
    }
    const int excl = base_s + lds[t] - v;
    if (i < N_NODE) { off[i] = excl; cursor[i] = excl; }
    if (i == N_NODE - 1) off[N_NODE] = excl + v;   // = N_EDGE
}

// ---------------------------------------------------------------------------
// Kernel 4: per-edge alpha + CSR fill.  FOUR lanes per edge (16 dims each).
// recs stores PRE-SCALED row offsets (sub*64, rel*64, tidx*64).
// ---------------------------------------------------------------------------
__global__ __launch_bounds__(256) void alpha_fill(const int* __restrict__ edges,
                                                  const int* __restrict__ q_tau_p,
                                                  const uint* __restrict__ A_node_bf,
                                                  const uint* __restrict__ rel_attn_bf,
                                                  const uint* __restrict__ qr_attn_bf,
                                                  const uint* __restrict__ tau_attn_bf,
                                                  const float* __restrict__ w_alpha_w,
                                                  const float* __restrict__ w_alpha_b,
                                                  int* __restrict__ cursor,
                                                  int4* __restrict__ recs) {
    const int t = threadIdx.x;
    const int q = t & 3;                        // lane-in-edge: dims [q*16, q*16+16)
    const int e = blockIdx.x * 64 + (t >> 2);   // 64 edges per 256-thread block
    if (e >= N_EDGE) return;

    const int* ed = edges + (size_t)e * 7;
    const int r_idx = ed[0];
    const int rel   = ed[2];
    const int tau   = ed[4];
    const int sub   = ed[5];
    const int obj   = ed[6];
    const int q_tau = *q_tau_p;
    const int tidx  = (tau >= 0) ? tau : q_tau;

    const uint4*  pa = (const uint4*)(A_node_bf  + (size_t)sub * 32) + q * 2;
    const uint4*  pr = (const uint4*)(rel_attn_bf + rel   * 32) + q * 2;
    const uint4*  pq = (const uint4*)(qr_attn_bf  + r_idx * 32) + q * 2;
    const uint4*  pt = (const uint4*)(tau_attn_bf + tidx  * 32) + q * 2;
    const float4* wv = (const float4*)w_alpha_w + q * 4;

    float acc = 0.f;

#define DOT_UINT(va, vr, vq, vt, wlo, whi) do {                                  \
        const float x0 = bfl(va) + bfl(vr) + bfl(vq) + bfl(vt);                  \
        const float x1 = bfh(va) + bfh(vr) + bfh(vq) + bfh(vt);                  \
        acc = fmaf(fmaxf(x0, 0.f), (wlo), fmaf(fmaxf(x1, 0.f), (whi), acc));     \
    } while (0)

    #pragma unroll
    for (int c = 0; c < 2; ++c) {
        const uint4  ua = pa[c];
        const uint4  ur = pr[c];
        const uint4  uq = pq[c];
        const uint4  ut = pt[c];
        const float4 w0 = wv[c * 2];
        const float4 w1 = wv[c * 2 + 1];
        DOT_UINT(ua.x, ur.x, uq.x, ut.x, w0.x, w0.y);
        DOT_UINT(ua.y, ur.y, uq.y, ut.y, w0.z, w0.w);
        DOT_UINT(ua.z, ur.z, uq.z, ut.z, w1.x, w1.y);
        DOT_UINT(ua.w, ur.w, uq.w, ut.w, w1.z, w1.w);
    }
#undef DOT_UINT

    // reduce across the quad (lanes q=0..3 of this edge)
    acc += __shfl_xor(acc, 1, 64);
    acc += __shfl_xor(acc, 2, 64);

    if (q == 0) {
        const float alpha = 1.f / (1.f + __expf(-(acc + w_alpha_b[0])));
        const int pos = atomicAdd(&cursor[obj], 1);
        recs[pos] = make_int4(sub * 64, rel * 64, tidx * 64, __float_as_int(alpha));
    }
}

// ---------------------------------------------------------------------------
// Kernel 5: FUSED aggregate + final GEMM.  (256 thr, 4 waves, 16 nodes/block.)
// v5: the block's CONTIGUOUS rec range [off[tile], off[tile+16]) is preloaded
//     into LDS (coalesced int4 loads, cap 768 = 12 KB, global fallback for the
//     never-in-practice overflow). Phase-1 reads recs via LDS broadcast ->
//     the global rec load leaves the serial rec->gather chain; only the
//     independent table gathers remain on it. Body = round-4 unroll-2 (best).
// ---------------------------------------------------------------------------
__global__ __launch_bounds__(256) void agg_gemm(const int* __restrict__ off,
                                                const int4* __restrict__ recs,
                                                const uint* __restrict__ hid_bf,
                                                const uint* __restrict__ rel_msg_bf,
                                                const uint* __restrict__ tau_msg_bf,
                                                const ushort* __restrict__ wfrag,
                                                float* __restrict__ out) {
    __shared__ uint lagg[2 * 16 * 64];   // 8 KB: [half][node16][64 uints], swizzled
    __shared__ int4 lrec[REC_CAP];       // 12 KB

    const int wave = threadIdx.x >> 6;
    const int lane = threadIdx.x & 63;          // dims 2*lane, 2*lane+1
    const int tile = blockIdx.x * 16;

    // ---- preload this block's rec range (contiguous in CSR order) ----
    const int base = off[tile];
    const int cnt  = off[tile + 16] - base;     // N_NODE % 16 == 0
    const int ldn  = min(cnt, REC_CAP);
    for (int i = threadIdx.x; i < ldn; i += 256)
        lrec[i] = recs[base + i];
    __syncthreads();

#define ACC_EDGE2(rA, rB, haveB) do {                                            \
        const uint hA = hid_bf[(uint)rA.x + lane];                               \
        const uint eA = rel_msg_bf[rA.y + lane];                                 \
        const uint uA = tau_msg_bf[rA.z + lane];                                 \
        const float alA = __int_as_float(rA.w);                                  \
        const float m0A = bfl(hA) + bfl(eA) + bfl(uA);                           \
        const float m1A = bfh(hA) + bfh(eA) + bfh(uA);                           \
        t0 += m0A;  t1 += m1A;                                                   \
        a0 = fmaf(alA, m0A, a0);  a1 = fmaf(alA, m1A, a1);                       \
        if (haveB) {                                                             \
            const uint hB = hid_bf[(uint)rB.x + lane];                           \
            const uint eB = rel_msg_bf[rB.y + lane];                             \
            const uint uB = tau_msg_bf[rB.z + lane];                             \
            const float alB = __int_as_float(rB.w);                              \
            const float m0B = bfl(hB) + bfl(eB) + bfl(uB);                       \
            const float m1B = bfh(hB) + bfh(eB) + bfh(uB);                       \
            t0 += m0B;  t1 += m1B;                                               \
            a0 = fmaf(alB, m0B, a0);  a1 = fmaf(alB, m1B, a1);                   \
        }                                                                        \
    } while (0)

    // ---- phase 1: aggregate (4 nodes per wave, unroll-2, recs from LDS) ----
    #pragma unroll
    for (int k = 0; k < 4; ++k) {
        const int n16 = wave * 4 + k;
        const int n = tile + n16;
        const int j0 = off[n] - base;
        const int j1 = off[n + 1] - base;

        float t0 = 0.f, t1 = 0.f;   // sum m
        float a0 = 0.f, a1 = 0.f;   // sum alpha*m

        if (j1 <= REC_CAP) {
            int j = j0;
            for (; j + 1 < j1; j += 2) {
                const int4 rA = lrec[j];
                const int4 rB = lrec[j + 1];
                ACC_EDGE2(rA, rB, true);
            }
            if (j < j1) {
                const int4 rA = lrec[j];
                const int4 rB = rA;
                ACC_EDGE2(rA, rB, false);
            }
        } else {
            // overflow fallback (essentially never taken; correctness only)
            int j = j0;
            for (; j + 1 < j1; j += 2) {
                const int4 rA = recs[base + j];
                const int4 rB = recs[base + j + 1];
                ACC_EDGE2(rA, rB, true);
            }
            if (j < j1) {
                const int4 rA = recs[base + j];
                const int4 rB = rA;
                ACC_EDGE2(rA, rB, false);
            }
        }

        const int gw = (((lane >> 2) ^ (n16 & 7)) << 2) | (lane & 3);
        lagg[n16 * 64 + gw]        = pack2(a0, a1);
        lagg[1024 + n16 * 64 + gw] = pack2(t0 - a0, t1 - a1);
    }
#undef ACC_EDGE2
    __syncthreads();

    // ---- phase 2: GEMM (wave w: half = w&1, ct in [(w>>1)*4, +4)) ----
    const int half = wave & 1;
    const int ctg  = (wave >> 1) * 4;
    const int m    = lane & 15;
    const int quad = lane >> 4;

    bf16x8 bfrag[4];
    #pragma unroll
    for (int ks = 0; ks < 4; ++ks) {
        const int g = (ks * 4 + quad) ^ (m & 7);
        bfrag[ks] = *(const bf16x8*)&lagg[half * 1024 + m * 64 + g * 4];
    }

    f32x4 acc[4] = {};
    #pragma unroll
    for (int ks = 0; ks < 4; ++ks) {
        #pragma unroll
        for (int c = 0; c < 4; ++c) {
            const bf16x8 wfr = *(const bf16x8*)(wfrag +
                ((size_t)(((half * 8 + ctg + c) * 4 + ks) * 64 + lane)) * 8);
            acc[c] = __builtin_amdgcn_mfma_f32_16x16x32_bf16(wfr, bfrag[ks], acc[c], 0, 0, 0);
        }
    }

    // D: col (lane&15) = node, row (quad*4+r) = out dim within (ctg+c)*16 block
    float* O = out + (size_t)half * N_NODE * 128 + (size_t)(tile + m) * 128;
    #pragma unroll
    for (int c = 0; c < 4; ++c)
        *(f32x4*)(O + (ctg + c) * 16 + quad * 4) = acc[c];
}

// ---------------------------------------------------------------------------
extern "C" void kernel_launch(void* const* d_in, const int* in_sizes, int n_in,
                              void* d_out, int out_size, void* d_ws, size_t ws_size,
                              hipStream_t stream) {
    const int*   q_rel      = (const int*)d_in[1];
    const int*   q_tau_p    = (const int*)d_in[2];
    const float* hidden     = (const float*)d_in[3];
    const int*   edges      = (const int*)d_in[4];
    const float* rela_embed = (const float*)d_in[7];
    const float* Ws_w       = (const float*)d_in[8];
    const float* Wr_w       = (const float*)d_in[9];
    const float* Wqr_w      = (const float*)d_in[10];
    const float* Wqr_b      = (const float*)d_in[11];
    const float* Wtau_w     = (const float*)d_in[12];
    const float* w_alpha_w  = (const float*)d_in[13];
    const float* w_alpha_b  = (const float*)d_in[14];
    const float* W_h_w      = (const float*)d_in[15];
    const float* W_h_s_w    = (const float*)d_in[16];
    const float* w_t1       = (const float*)d_in[17];
    const float* b_t1       = (const float*)d_in[18];
    const float* w_t2       = (const float*)d_in[19];
    const float* b_t2       = (const float*)d_in[20];

    // ---- workspace layout (16B-aligned chunks) ----
    char* p = (char*)d_ws;
    uint* hid_bf      = (uint*)p;                 p += (size_t)N_NODE * 64 * 4;        // 25.6 MB
    uint* A_node_bf   = (uint*)p;                 p += (size_t)N_NODE * 32 * 4;        // 12.8 MB
    int4* recs        = (int4*)p;                 p += (size_t)N_EDGE * 16;            // 8 MB
    uint* rel_attn_bf = (uint*)p;                 p += N_RELTAB * 32 * 4;
    uint* qr_attn_bf  = (uint*)p;                 p += N_QRY * 32 * 4;
    uint* tau_attn_bf = (uint*)p;                 p += N_TAU * 32 * 4;
    uint* rel_msg_bf  = (uint*)p;                 p += N_RELTAB * 64 * 4;
    uint* tau_msg_bf  = (uint*)p;                 p += N_TAU * 64 * 4;
    ushort* wfrag_bf  = (ushort*)p;               p += (size_t)2 * 2048 * 8 * 2;       // 64 KB
    ushort* wsT_bf    = (ushort*)p;               p += (size_t)64 * 128 * 2;           // 16 KB
    int*  count       = (int*)p;                  p += N_NODE * 4;
    int*  off         = (int*)p;                  p += (N_NODE + 1) * 4;
    int*  cursor      = (int*)p;                  p += N_NODE * 4;
    int*  partial     = (int*)p;                  p += N_SCAN_BLKS * 4;
    int*  blk_off     = (int*)p;                  p += N_SCAN_BLKS * 4;

    hipMemsetAsync(count, 0, (size_t)N_NODE * sizeof(int), stream);

    build_count<<<dim3(NB_TABLES + NB_COUNT), dim3(256), 0, stream>>>(
        q_rel, q_tau_p, rela_embed, Wr_w, Wqr_w, Wqr_b, Wtau_w,
        w_t1, b_t1, w_t2, b_t2, W_h_w, W_h_s_w, Ws_w, edges,
        rel_attn_bf, qr_attn_bf, tau_attn_bf, rel_msg_bf, tau_msg_bf,
        wfrag_bf, wsT_bf, count);

    node_attn_scan<<<dim3(NB_NODE + N_SCAN_BLKS), dim3(256), 0, stream>>>(
        hidden, wsT_bf, hid_bf, (ushort*)A_node_bf, count, partial);

    scan_apply<<<dim3(N_SCAN_BLKS), dim3(SCAN_BLK), 0, stream>>>(count, partial, off, cursor);

    alpha_fill<<<dim3((N_EDGE + 63) / 64), dim3(256), 0, stream>>>(
        edges, q_tau_p, A_node_bf, rel_attn_bf, qr_attn_bf, tau_attn_bf,
        w_alpha_w, w_alpha_b, cursor, recs);

    agg_gemm<<<dim3(N_NODE / 16), dim3(256), 0, stream>>>(
        off, recs, hid_bf, rel_msg_bf, tau_msg_bf, wfrag_bf, (float*)d_out);
}